// Round 2
// baseline (87.063 us; speedup 1.0000x reference)
//
#include <hip/hip_runtime.h>
#include <math.h>

#define OUT_H 7
#define OUT_W 7
#define NBINS 49
#define CCH   256

struct __align__(16) BoxHeader {
    unsigned long long planeBase;  // byte address of feat + b*C*H*W elements
    unsigned int       chanBytes;  // H*W*4
    unsigned int       pad;
};
struct __align__(16) BinParam {
    unsigned int o[4];   // byte offsets of v00,v01,v10,v11 within a channel plane
    float        w[4];   // blend weights (0 if sample invalid)
};

// ---------- pass 1: per-(box,bin) parameter precompute (tiny) ----------
__global__ void msroi_pre_kernel(const float* __restrict__ f0,
                                 const float* __restrict__ f1,
                                 const float* __restrict__ f2,
                                 const float* __restrict__ f3,
                                 const float* __restrict__ boxes,
                                 BoxHeader* __restrict__ hdrs,
                                 BinParam*  __restrict__ prm,
                                 int M, int L)
{
    int tid = blockIdx.x * blockDim.x + threadIdx.x;
    if (tid >= M * NBINS) return;
    int m   = tid / NBINS;
    int bin = tid - m * NBINS;
    int yh  = bin / OUT_W;
    int xw  = bin - yh * OUT_W;

    float bx1 = boxes[m*4+0], by1 = boxes[m*4+1];
    float bx2 = boxes[m*4+2], by2 = boxes[m*4+3];

    float sz  = sqrtf((bx2 - bx1 + 1.0f) * (by2 - by1 + 1.0f));
    float lvf = floorf(4.0f + log2f(sz / 224.0f) + 1e-8f);
    lvf = fminf(fmaxf(lvf, 2.0f), 5.0f);
    int lv = (int)lvf - 2;

    const float* feat; int H, W; float scale;
    switch (lv) {
        case 0:  feat = f0; H = 256; W = 256; scale = 0.25f;    break;
        case 1:  feat = f1; H = 128; W = 128; scale = 0.125f;   break;
        case 2:  feat = f2; H = 64;  W = 64;  scale = 0.0625f;  break;
        default: feat = f3; H = 32;  W = 32;  scale = 0.03125f; break;
    }

    if (bin == 0) {
        int b = m / L;
        BoxHeader h;
        h.planeBase = (unsigned long long)(const void*)(feat + (size_t)b * CCH * H * W);
        h.chanBytes = (unsigned int)(H * W * 4);
        h.pad = 0;
        hdrs[m] = h;
    }

    float x1 = bx1 * scale, y1 = by1 * scale;
    float x2 = bx2 * scale, y2 = by2 * scale;
    float roi_w = fmaxf(x2 - x1, 1.0f);
    float roi_h = fmaxf(y2 - y1, 1.0f);
    float bin_w = roi_w * (1.0f / OUT_W);
    float bin_h = roi_h * (1.0f / OUT_H);
    float sx = x1 + ((float)xw + 0.5f) * bin_w;
    float sy = y1 + ((float)yh + 0.5f) * bin_h;

    // _bilinear_axis(x)
    bool  vx  = (sx >= -1.0f) && (sx <= (float)W);
    float scx = fmaxf(sx, 0.0f);
    int   xlr = (int)floorf(scx);
    bool  hxf = xlr >= (W - 1);
    int   xl  = hxf ? (W - 1) : xlr;
    int   xh  = hxf ? (W - 1) : (xlr + 1);
    float lx  = hxf ? 0.0f : (scx - (float)xlr);

    // _bilinear_axis(y)
    bool  vy  = (sy >= -1.0f) && (sy <= (float)H);
    float scy = fmaxf(sy, 0.0f);
    int   ylr = (int)floorf(scy);
    bool  hyf = ylr >= (H - 1);
    int   yl  = hyf ? (H - 1) : ylr;
    int   yhh = hyf ? (H - 1) : (ylr + 1);
    float ly  = hyf ? 0.0f : (scy - (float)ylr);

    float hy = 1.0f - ly, hx = 1.0f - lx;
    bool  valid = vx && vy;

    BinParam p;
    p.o[0] = (unsigned)((yl  * W + xl) * 4);
    p.o[1] = (unsigned)((yl  * W + xh) * 4);
    p.o[2] = (unsigned)((yhh * W + xl) * 4);
    p.o[3] = (unsigned)((yhh * W + xh) * 4);
    p.w[0] = valid ? (hy * hx) : 0.0f;
    p.w[1] = valid ? (hy * lx) : 0.0f;
    p.w[2] = valid ? (ly * hx) : 0.0f;
    p.w[3] = valid ? (ly * lx) : 0.0f;
    prm[tid] = p;
}

// ---------- pass 2: gather + blend (hot) ----------
__global__ __launch_bounds__(256)
void msroi_gather_kernel(const BoxHeader* __restrict__ hdrs,
                         const BinParam*  __restrict__ prm,
                         float* __restrict__ out)
{
    int m = blockIdx.y;                               // box (uniform per block)
    int e = blockIdx.x * 256 + threadIdx.x;           // element within box, < 12544
    BoxHeader h = hdrs[m];

    unsigned c   = (unsigned)e / NBINS;               // magic-mul div
    unsigned bin = (unsigned)e - c * NBINS;
    BinParam p = prm[m * NBINS + (int)bin];

    const char* plane = (const char*)(h.planeBase
                        + (unsigned long long)c * (unsigned long long)h.chanBytes);
    float v0 = *(const float*)(plane + p.o[0]);
    float v1 = *(const float*)(plane + p.o[1]);
    float v2 = *(const float*)(plane + p.o[2]);
    float v3 = *(const float*)(plane + p.o[3]);

    out[(size_t)m * (NBINS * CCH) + e] =
        v0 * p.w[0] + v1 * p.w[1] + v2 * p.w[2] + v3 * p.w[3];
}

// ---------- fallback: original monolithic kernel (used if ws too small) ----------
__global__ void msroi_align_kernel(const float* __restrict__ f0,
                                   const float* __restrict__ f1,
                                   const float* __restrict__ f2,
                                   const float* __restrict__ f3,
                                   const float* __restrict__ boxes,
                                   float* __restrict__ out,
                                   int M, int C, int L, int total)
{
    int idx = blockIdx.x * blockDim.x + threadIdx.x;
    if (idx >= total) return;

    int xw = idx % OUT_W;
    int t  = idx / OUT_W;
    int yh = t % OUT_H;
    t /= OUT_H;
    int c = t % C;
    int m = t / C;
    int b = m / L;

    float bx1 = boxes[m*4+0], by1 = boxes[m*4+1];
    float bx2 = boxes[m*4+2], by2 = boxes[m*4+3];

    float sz  = sqrtf((bx2 - bx1 + 1.0f) * (by2 - by1 + 1.0f));
    float lvf = floorf(4.0f + log2f(sz / 224.0f) + 1e-8f);
    lvf = fminf(fmaxf(lvf, 2.0f), 5.0f);
    int lv = (int)lvf - 2;

    const float* feat; int H, W; float scale;
    switch (lv) {
        case 0:  feat = f0; H = 256; W = 256; scale = 0.25f;    break;
        case 1:  feat = f1; H = 128; W = 128; scale = 0.125f;   break;
        case 2:  feat = f2; H = 64;  W = 64;  scale = 0.0625f;  break;
        default: feat = f3; H = 32;  W = 32;  scale = 0.03125f; break;
    }

    float x1 = bx1 * scale, y1 = by1 * scale;
    float x2 = bx2 * scale, y2 = by2 * scale;
    float roi_w = fmaxf(x2 - x1, 1.0f);
    float roi_h = fmaxf(y2 - y1, 1.0f);
    float bin_w = roi_w * (1.0f / OUT_W);
    float bin_h = roi_h * (1.0f / OUT_H);
    float sx = x1 + ((float)xw + 0.5f) * bin_w;
    float sy = y1 + ((float)yh + 0.5f) * bin_h;

    bool  vx  = (sx >= -1.0f) && (sx <= (float)W);
    float scx = fmaxf(sx, 0.0f);
    int   xlr = (int)floorf(scx);
    bool  hxf = xlr >= (W - 1);
    int   xl  = hxf ? (W - 1) : xlr;
    int   xh  = hxf ? (W - 1) : (xlr + 1);
    float lx  = hxf ? 0.0f : (scx - (float)xlr);

    bool  vy  = (sy >= -1.0f) && (sy <= (float)H);
    float scy = fmaxf(sy, 0.0f);
    int   ylr = (int)floorf(scy);
    bool  hyf = ylr >= (H - 1);
    int   yl  = hyf ? (H - 1) : ylr;
    int   yhh = hyf ? (H - 1) : (ylr + 1);
    float ly  = hyf ? 0.0f : (scy - (float)ylr);

    float val = 0.0f;
    if (vx && vy) {
        size_t base = ((size_t)b * (size_t)C + (size_t)c) * (size_t)(H * W);
        const float* p = feat + base;
        float v00 = p[(size_t)yl  * W + xl];
        float v01 = p[(size_t)yl  * W + xh];
        float v10 = p[(size_t)yhh * W + xl];
        float v11 = p[(size_t)yhh * W + xh];
        float hy = 1.0f - ly, hx = 1.0f - lx;
        val = v00 * (hy * hx) + v01 * (hy * lx) + v10 * (ly * hx) + v11 * (ly * lx);
    }
    out[idx] = val;
}

extern "C" void kernel_launch(void* const* d_in, const int* in_sizes, int n_in,
                              void* d_out, int out_size, void* d_ws, size_t ws_size,
                              hipStream_t stream) {
    const float* f0    = (const float*)d_in[0];
    const float* f1    = (const float*)d_in[1];
    const float* f2    = (const float*)d_in[2];
    const float* f3    = (const float*)d_in[3];
    const float* boxes = (const float*)d_in[4];
    float* out = (float*)d_out;

    const int N = 2;
    const int M = in_sizes[4] / 4;   // total boxes (N*L)
    const int L = M / N;             // boxes per batch
    const int total = M * CCH * NBINS;

    size_t prmBytes = (size_t)M * NBINS * sizeof(BinParam);
    size_t hdrBytes = (size_t)M * sizeof(BoxHeader);
    size_t need = prmBytes + hdrBytes;

    if (ws_size >= need) {
        BinParam*  prm  = (BinParam*)d_ws;
        BoxHeader* hdrs = (BoxHeader*)((char*)d_ws + prmBytes);

        int preThreads = M * NBINS;
        msroi_pre_kernel<<<(preThreads + 255) / 256, 256, 0, stream>>>(
            f0, f1, f2, f3, boxes, hdrs, prm, M, L);

        dim3 grid(NBINS, M);  // 12544 elems/box / 256 thr = 49 blocks per box
        msroi_gather_kernel<<<grid, 256, 0, stream>>>(hdrs, prm, out);
    } else {
        int block = 256;
        int grid = (total + block - 1) / block;
        msroi_align_kernel<<<grid, block, 0, stream>>>(f0, f1, f2, f3, boxes, out,
                                                       M, CCH, L, total);
    }
}

// Round 3
// 85.729 us; speedup vs baseline: 1.0156x; 1.0156x over previous
//
#include <hip/hip_runtime.h>
#include <math.h>

#define OUT_H 7
#define OUT_W 7
#define NBINS 49
#define CCH   256

typedef float f32x2 __attribute__((ext_vector_type(2)));
struct __attribute__((packed)) F2A { f32x2 v; } __attribute__((aligned(4)));

struct __align__(16) BoxHeader {
    unsigned long long planeBase;  // byte address of feat + b*C*H*W elements
    unsigned int       chanBytes;  // H*W*4
    unsigned int       pad;
};
struct __align__(16) BinParam {
    unsigned int o0;   // byte offset of row-A pair (covers vA0,vA1)
    unsigned int o1;   // byte offset of row-B pair (covers vB0,vB1)
    float w0, w1;      // weights for row-A pair
    float w2, w3;      // weights for row-B pair
    unsigned int pad0, pad1;
};

// ---------- pass 1: per-(box,bin) parameter precompute (tiny) ----------
__global__ void msroi_pre_kernel(const float* __restrict__ f0,
                                 const float* __restrict__ f1,
                                 const float* __restrict__ f2,
                                 const float* __restrict__ f3,
                                 const float* __restrict__ boxes,
                                 BoxHeader* __restrict__ hdrs,
                                 BinParam*  __restrict__ prm,
                                 int M, int L)
{
    int tid = blockIdx.x * blockDim.x + threadIdx.x;
    if (tid >= M * NBINS) return;
    int m   = tid / NBINS;
    int bin = tid - m * NBINS;
    int yh  = bin / OUT_W;
    int xw  = bin - yh * OUT_W;

    float bx1 = boxes[m*4+0], by1 = boxes[m*4+1];
    float bx2 = boxes[m*4+2], by2 = boxes[m*4+3];

    float sz  = sqrtf((bx2 - bx1 + 1.0f) * (by2 - by1 + 1.0f));
    float lvf = floorf(4.0f + log2f(sz / 224.0f) + 1e-8f);
    lvf = fminf(fmaxf(lvf, 2.0f), 5.0f);
    int lv = (int)lvf - 2;

    const float* feat; int H, W; float scale;
    switch (lv) {
        case 0:  feat = f0; H = 256; W = 256; scale = 0.25f;    break;
        case 1:  feat = f1; H = 128; W = 128; scale = 0.125f;   break;
        case 2:  feat = f2; H = 64;  W = 64;  scale = 0.0625f;  break;
        default: feat = f3; H = 32;  W = 32;  scale = 0.03125f; break;
    }

    if (bin == 0) {
        int b = m / L;
        BoxHeader h;
        h.planeBase = (unsigned long long)(const void*)(feat + (size_t)b * CCH * H * W);
        h.chanBytes = (unsigned int)(H * W * 4);
        h.pad = 0;
        hdrs[m] = h;
    }

    float x1 = bx1 * scale, y1 = by1 * scale;
    float x2 = bx2 * scale, y2 = by2 * scale;
    float roi_w = fmaxf(x2 - x1, 1.0f);
    float roi_h = fmaxf(y2 - y1, 1.0f);
    float bin_w = roi_w * (1.0f / OUT_W);
    float bin_h = roi_h * (1.0f / OUT_H);
    float sx = x1 + ((float)xw + 0.5f) * bin_w;
    float sy = y1 + ((float)yh + 0.5f) * bin_h;

    // _bilinear_axis(x): pair covers (xA, xA+1)
    bool  vx  = (sx >= -1.0f) && (sx <= (float)W);
    float scx = fmaxf(sx, 0.0f);
    int   xlr = (int)floorf(scx);
    bool  hxf = xlr >= (W - 1);
    float lx  = hxf ? 0.0f : (scx - (float)xlr);
    // normal: pair at xl -> weights (1-lx, lx)
    // hi-clamp: sample is p[W-1] with weight 1; place pair at W-2 -> (0, 1)
    int   xA  = hxf ? (W - 2) : xlr;          // xlr <= W-2 when !hxf
    float wxA = hxf ? 0.0f : (1.0f - lx);
    float wxB = hxf ? 1.0f : lx;

    // _bilinear_axis(y): two row loads at rows rA, rB
    bool  vy  = (sy >= -1.0f) && (sy <= (float)H);
    float scy = fmaxf(sy, 0.0f);
    int   ylr = (int)floorf(scy);
    bool  hyf = ylr >= (H - 1);
    int   rA  = hyf ? (H - 1) : ylr;
    int   rB  = hyf ? (H - 1) : (ylr + 1);
    float ly  = hyf ? 0.0f : (scy - (float)ylr);
    float wyA = 1.0f - ly;                    // hi-clamp: ly=0 -> (1,0)
    float wyB = ly;

    float vmask = (vx && vy) ? 1.0f : 0.0f;

    BinParam p;
    p.o0 = (unsigned)((rA * W + xA) * 4);
    p.o1 = (unsigned)((rB * W + xA) * 4);
    p.w0 = vmask * wyA * wxA;
    p.w1 = vmask * wyA * wxB;
    p.w2 = vmask * wyB * wxA;
    p.w3 = vmask * wyB * wxB;
    p.pad0 = 0; p.pad1 = 0;
    prm[tid] = p;
}

// ---------- pass 2: gather + blend (hot) ----------
__global__ __launch_bounds__(256)
void msroi_gather_kernel(const BoxHeader* __restrict__ hdrs,
                         const BinParam*  __restrict__ prm,
                         float* __restrict__ out)
{
    int m = blockIdx.y;                               // box (uniform per block)
    int e = blockIdx.x * 256 + threadIdx.x;           // element within box, < 12544
    BoxHeader h = hdrs[m];

    unsigned c   = (unsigned)e / NBINS;               // magic-mul div
    unsigned bin = (unsigned)e - c * NBINS;
    BinParam p = prm[m * NBINS + (int)bin];

    const char* plane = (const char*)(h.planeBase
                        + (unsigned long long)c * (unsigned long long)h.chanBytes);
    f32x2 r0 = ((const F2A*)(plane + p.o0))->v;       // (vA0, vA1)
    f32x2 r1 = ((const F2A*)(plane + p.o1))->v;       // (vB0, vB1)

    out[(size_t)m * (NBINS * CCH) + e] =
        r0.x * p.w0 + r0.y * p.w1 + r1.x * p.w2 + r1.y * p.w3;
}

// ---------- fallback: monolithic kernel (used only if ws too small) ----------
__global__ void msroi_align_kernel(const float* __restrict__ f0,
                                   const float* __restrict__ f1,
                                   const float* __restrict__ f2,
                                   const float* __restrict__ f3,
                                   const float* __restrict__ boxes,
                                   float* __restrict__ out,
                                   int M, int C, int L, int total)
{
    int idx = blockIdx.x * blockDim.x + threadIdx.x;
    if (idx >= total) return;

    int xw = idx % OUT_W;
    int t  = idx / OUT_W;
    int yh = t % OUT_H;
    t /= OUT_H;
    int c = t % C;
    int m = t / C;
    int b = m / L;

    float bx1 = boxes[m*4+0], by1 = boxes[m*4+1];
    float bx2 = boxes[m*4+2], by2 = boxes[m*4+3];

    float sz  = sqrtf((bx2 - bx1 + 1.0f) * (by2 - by1 + 1.0f));
    float lvf = floorf(4.0f + log2f(sz / 224.0f) + 1e-8f);
    lvf = fminf(fmaxf(lvf, 2.0f), 5.0f);
    int lv = (int)lvf - 2;

    const float* feat; int H, W; float scale;
    switch (lv) {
        case 0:  feat = f0; H = 256; W = 256; scale = 0.25f;    break;
        case 1:  feat = f1; H = 128; W = 128; scale = 0.125f;   break;
        case 2:  feat = f2; H = 64;  W = 64;  scale = 0.0625f;  break;
        default: feat = f3; H = 32;  W = 32;  scale = 0.03125f; break;
    }

    float x1 = bx1 * scale, y1 = by1 * scale;
    float x2 = bx2 * scale, y2 = by2 * scale;
    float roi_w = fmaxf(x2 - x1, 1.0f);
    float roi_h = fmaxf(y2 - y1, 1.0f);
    float bin_w = roi_w * (1.0f / OUT_W);
    float bin_h = roi_h * (1.0f / OUT_H);
    float sx = x1 + ((float)xw + 0.5f) * bin_w;
    float sy = y1 + ((float)yh + 0.5f) * bin_h;

    bool  vx  = (sx >= -1.0f) && (sx <= (float)W);
    float scx = fmaxf(sx, 0.0f);
    int   xlr = (int)floorf(scx);
    bool  hxf = xlr >= (W - 1);
    int   xl  = hxf ? (W - 1) : xlr;
    int   xh  = hxf ? (W - 1) : (xlr + 1);
    float lx  = hxf ? 0.0f : (scx - (float)xlr);

    bool  vy  = (sy >= -1.0f) && (sy <= (float)H);
    float scy = fmaxf(sy, 0.0f);
    int   ylr = (int)floorf(scy);
    bool  hyf = ylr >= (H - 1);
    int   yl  = hyf ? (H - 1) : ylr;
    int   yhh = hyf ? (H - 1) : (ylr + 1);
    float ly  = hyf ? 0.0f : (scy - (float)ylr);

    float val = 0.0f;
    if (vx && vy) {
        size_t base = ((size_t)b * (size_t)C + (size_t)c) * (size_t)(H * W);
        const float* p = feat + base;
        float v00 = p[(size_t)yl  * W + xl];
        float v01 = p[(size_t)yl  * W + xh];
        float v10 = p[(size_t)yhh * W + xl];
        float v11 = p[(size_t)yhh * W + xh];
        float hy = 1.0f - ly, hx = 1.0f - lx;
        val = v00 * (hy * hx) + v01 * (hy * lx) + v10 * (ly * hx) + v11 * (ly * lx);
    }
    out[idx] = val;
}

extern "C" void kernel_launch(void* const* d_in, const int* in_sizes, int n_in,
                              void* d_out, int out_size, void* d_ws, size_t ws_size,
                              hipStream_t stream) {
    const float* f0    = (const float*)d_in[0];
    const float* f1    = (const float*)d_in[1];
    const float* f2    = (const float*)d_in[2];
    const float* f3    = (const float*)d_in[3];
    const float* boxes = (const float*)d_in[4];
    float* out = (float*)d_out;

    const int N = 2;
    const int M = in_sizes[4] / 4;   // total boxes (N*L)
    const int L = M / N;             // boxes per batch
    const int total = M * CCH * NBINS;

    size_t prmBytes = (size_t)M * NBINS * sizeof(BinParam);
    size_t hdrBytes = (size_t)M * sizeof(BoxHeader);
    size_t need = prmBytes + hdrBytes;

    if (ws_size >= need) {
        BinParam*  prm  = (BinParam*)d_ws;
        BoxHeader* hdrs = (BoxHeader*)((char*)d_ws + prmBytes);

        int preThreads = M * NBINS;
        msroi_pre_kernel<<<(preThreads + 255) / 256, 256, 0, stream>>>(
            f0, f1, f2, f3, boxes, hdrs, prm, M, L);

        dim3 grid(NBINS, M);  // 12544 elems/box / 256 thr = 49 blocks per box
        msroi_gather_kernel<<<grid, 256, 0, stream>>>(hdrs, prm, out);
    } else {
        int block = 256;
        int grid = (total + block - 1) / block;
        msroi_align_kernel<<<grid, block, 0, stream>>>(f0, f1, f2, f3, boxes, out,
                                                       M, CCH, L, total);
    }
}

// Round 4
// 56.058 us; speedup vs baseline: 1.5531x; 1.5293x over previous
//
#include <hip/hip_runtime.h>
#include <math.h>

#define OUT_H 7
#define OUT_W 7
#define NBINS 49
#define CCH   256
// grid.x padded to a multiple of 8 so that linear block id = x + GRIDX*y
// maps to XCD = x % 8, independent of the box index y. This gives every
// channel-slice a fixed XCD -> feature lines shared across overlapping
// boxes are fetched into ONE L2, not eight.
#define GRIDX 56

typedef float f32x2 __attribute__((ext_vector_type(2)));
struct __attribute__((packed)) F2A { f32x2 v; } __attribute__((aligned(4)));

struct __align__(16) BoxHeader {
    unsigned long long planeBase;  // byte address of feat + b*C*H*W elements
    unsigned int       chanBytes;  // H*W*4
    unsigned int       pad;
};
struct __align__(16) BinParam {
    unsigned int o0;   // byte offset of row-A pair (covers vA0,vA1)
    unsigned int o1;   // byte offset of row-B pair (covers vB0,vB1)
    float w0, w1;      // weights for row-A pair
    float w2, w3;      // weights for row-B pair
    unsigned int pad0, pad1;
};

// ---------- pass 1: per-(box,bin) parameter precompute (tiny) ----------
__global__ void msroi_pre_kernel(const float* __restrict__ f0,
                                 const float* __restrict__ f1,
                                 const float* __restrict__ f2,
                                 const float* __restrict__ f3,
                                 const float* __restrict__ boxes,
                                 BoxHeader* __restrict__ hdrs,
                                 BinParam*  __restrict__ prm,
                                 int M, int L)
{
    int tid = blockIdx.x * blockDim.x + threadIdx.x;
    if (tid >= M * NBINS) return;
    int m   = tid / NBINS;
    int bin = tid - m * NBINS;
    int yh  = bin / OUT_W;
    int xw  = bin - yh * OUT_W;

    float bx1 = boxes[m*4+0], by1 = boxes[m*4+1];
    float bx2 = boxes[m*4+2], by2 = boxes[m*4+3];

    float sz  = sqrtf((bx2 - bx1 + 1.0f) * (by2 - by1 + 1.0f));
    float lvf = floorf(4.0f + log2f(sz / 224.0f) + 1e-8f);
    lvf = fminf(fmaxf(lvf, 2.0f), 5.0f);
    int lv = (int)lvf - 2;

    const float* feat; int H, W; float scale;
    switch (lv) {
        case 0:  feat = f0; H = 256; W = 256; scale = 0.25f;    break;
        case 1:  feat = f1; H = 128; W = 128; scale = 0.125f;   break;
        case 2:  feat = f2; H = 64;  W = 64;  scale = 0.0625f;  break;
        default: feat = f3; H = 32;  W = 32;  scale = 0.03125f; break;
    }

    if (bin == 0) {
        int b = m / L;
        BoxHeader h;
        h.planeBase = (unsigned long long)(const void*)(feat + (size_t)b * CCH * H * W);
        h.chanBytes = (unsigned int)(H * W * 4);
        h.pad = 0;
        hdrs[m] = h;
    }

    float x1 = bx1 * scale, y1 = by1 * scale;
    float x2 = bx2 * scale, y2 = by2 * scale;
    float roi_w = fmaxf(x2 - x1, 1.0f);
    float roi_h = fmaxf(y2 - y1, 1.0f);
    float bin_w = roi_w * (1.0f / OUT_W);
    float bin_h = roi_h * (1.0f / OUT_H);
    float sx = x1 + ((float)xw + 0.5f) * bin_w;
    float sy = y1 + ((float)yh + 0.5f) * bin_h;

    // _bilinear_axis(x): pair covers (xA, xA+1)
    bool  vx  = (sx >= -1.0f) && (sx <= (float)W);
    float scx = fmaxf(sx, 0.0f);
    int   xlr = (int)floorf(scx);
    bool  hxf = xlr >= (W - 1);
    float lx  = hxf ? 0.0f : (scx - (float)xlr);
    int   xA  = hxf ? (W - 2) : xlr;
    float wxA = hxf ? 0.0f : (1.0f - lx);
    float wxB = hxf ? 1.0f : lx;

    // _bilinear_axis(y): two row loads at rows rA, rB
    bool  vy  = (sy >= -1.0f) && (sy <= (float)H);
    float scy = fmaxf(sy, 0.0f);
    int   ylr = (int)floorf(scy);
    bool  hyf = ylr >= (H - 1);
    int   rA  = hyf ? (H - 1) : ylr;
    int   rB  = hyf ? (H - 1) : (ylr + 1);
    float ly  = hyf ? 0.0f : (scy - (float)ylr);
    float wyA = 1.0f - ly;
    float wyB = ly;

    float vmask = (vx && vy) ? 1.0f : 0.0f;

    BinParam p;
    p.o0 = (unsigned)((rA * W + xA) * 4);
    p.o1 = (unsigned)((rB * W + xA) * 4);
    p.w0 = vmask * wyA * wxA;
    p.w1 = vmask * wyA * wxB;
    p.w2 = vmask * wyB * wxA;
    p.w3 = vmask * wyB * wxB;
    p.pad0 = 0; p.pad1 = 0;
    prm[tid] = p;
}

// ---------- pass 2: gather + blend (hot) ----------
__global__ __launch_bounds__(256)
void msroi_gather_kernel(const BoxHeader* __restrict__ hdrs,
                         const BinParam*  __restrict__ prm,
                         float* __restrict__ out)
{
    int e = blockIdx.x * 256 + threadIdx.x;           // element within box
    if (e >= NBINS * CCH) return;                     // padded blocks (49..55) exit
    int m = blockIdx.y;                               // box (uniform per block)
    BoxHeader h = hdrs[m];

    unsigned c   = (unsigned)e / NBINS;               // magic-mul div
    unsigned bin = (unsigned)e - c * NBINS;
    BinParam p = prm[m * NBINS + (int)bin];

    const char* plane = (const char*)(h.planeBase
                        + (unsigned long long)c * (unsigned long long)h.chanBytes);
    f32x2 r0 = ((const F2A*)(plane + p.o0))->v;       // (vA0, vA1)
    f32x2 r1 = ((const F2A*)(plane + p.o1))->v;       // (vB0, vB1)

    out[(size_t)m * (NBINS * CCH) + e] =
        r0.x * p.w0 + r0.y * p.w1 + r1.x * p.w2 + r1.y * p.w3;
}

// ---------- fallback: monolithic kernel (used only if ws too small) ----------
__global__ void msroi_align_kernel(const float* __restrict__ f0,
                                   const float* __restrict__ f1,
                                   const float* __restrict__ f2,
                                   const float* __restrict__ f3,
                                   const float* __restrict__ boxes,
                                   float* __restrict__ out,
                                   int M, int C, int L, int total)
{
    int idx = blockIdx.x * blockDim.x + threadIdx.x;
    if (idx >= total) return;

    int xw = idx % OUT_W;
    int t  = idx / OUT_W;
    int yh = t % OUT_H;
    t /= OUT_H;
    int c = t % C;
    int m = t / C;
    int b = m / L;

    float bx1 = boxes[m*4+0], by1 = boxes[m*4+1];
    float bx2 = boxes[m*4+2], by2 = boxes[m*4+3];

    float sz  = sqrtf((bx2 - bx1 + 1.0f) * (by2 - by1 + 1.0f));
    float lvf = floorf(4.0f + log2f(sz / 224.0f) + 1e-8f);
    lvf = fminf(fmaxf(lvf, 2.0f), 5.0f);
    int lv = (int)lvf - 2;

    const float* feat; int H, W; float scale;
    switch (lv) {
        case 0:  feat = f0; H = 256; W = 256; scale = 0.25f;    break;
        case 1:  feat = f1; H = 128; W = 128; scale = 0.125f;   break;
        case 2:  feat = f2; H = 64;  W = 64;  scale = 0.0625f;  break;
        default: feat = f3; H = 32;  W = 32;  scale = 0.03125f; break;
    }

    float x1 = bx1 * scale, y1 = by1 * scale;
    float x2 = bx2 * scale, y2 = by2 * scale;
    float roi_w = fmaxf(x2 - x1, 1.0f);
    float roi_h = fmaxf(y2 - y1, 1.0f);
    float bin_w = roi_w * (1.0f / OUT_W);
    float bin_h = roi_h * (1.0f / OUT_H);
    float sx = x1 + ((float)xw + 0.5f) * bin_w;
    float sy = y1 + ((float)yh + 0.5f) * bin_h;

    bool  vx  = (sx >= -1.0f) && (sx <= (float)W);
    float scx = fmaxf(sx, 0.0f);
    int   xlr = (int)floorf(scx);
    bool  hxf = xlr >= (W - 1);
    int   xl  = hxf ? (W - 1) : xlr;
    int   xh  = hxf ? (W - 1) : (xlr + 1);
    float lx  = hxf ? 0.0f : (scx - (float)xlr);

    bool  vy  = (sy >= -1.0f) && (sy <= (float)H);
    float scy = fmaxf(sy, 0.0f);
    int   ylr = (int)floorf(scy);
    bool  hyf = ylr >= (H - 1);
    int   yl  = hyf ? (H - 1) : ylr;
    int   yhh = hyf ? (H - 1) : (ylr + 1);
    float ly  = hyf ? 0.0f : (scy - (float)ylr);

    float val = 0.0f;
    if (vx && vy) {
        size_t base = ((size_t)b * (size_t)C + (size_t)c) * (size_t)(H * W);
        const float* p = feat + base;
        float v00 = p[(size_t)yl  * W + xl];
        float v01 = p[(size_t)yl  * W + xh];
        float v10 = p[(size_t)yhh * W + xl];
        float v11 = p[(size_t)yhh * W + xh];
        float hy = 1.0f - ly, hx = 1.0f - lx;
        val = v00 * (hy * hx) + v01 * (hy * lx) + v10 * (ly * hx) + v11 * (ly * lx);
    }
    out[idx] = val;
}

extern "C" void kernel_launch(void* const* d_in, const int* in_sizes, int n_in,
                              void* d_out, int out_size, void* d_ws, size_t ws_size,
                              hipStream_t stream) {
    const float* f0    = (const float*)d_in[0];
    const float* f1    = (const float*)d_in[1];
    const float* f2    = (const float*)d_in[2];
    const float* f3    = (const float*)d_in[3];
    const float* boxes = (const float*)d_in[4];
    float* out = (float*)d_out;

    const int N = 2;
    const int M = in_sizes[4] / 4;   // total boxes (N*L)
    const int L = M / N;             // boxes per batch
    const int total = M * CCH * NBINS;

    size_t prmBytes = (size_t)M * NBINS * sizeof(BinParam);
    size_t hdrBytes = (size_t)M * sizeof(BoxHeader);
    size_t need = prmBytes + hdrBytes;

    if (ws_size >= need) {
        BinParam*  prm  = (BinParam*)d_ws;
        BoxHeader* hdrs = (BoxHeader*)((char*)d_ws + prmBytes);

        int preThreads = M * NBINS;
        msroi_pre_kernel<<<(preThreads + 255) / 256, 256, 0, stream>>>(
            f0, f1, f2, f3, boxes, hdrs, prm, M, L);

        dim3 grid(GRIDX, M);  // padded: blocks 49..55 exit; XCD = blockIdx.x % 8
        msroi_gather_kernel<<<grid, 256, 0, stream>>>(hdrs, prm, out);
    } else {
        int block = 256;
        int grid = (total + block - 1) / block;
        msroi_align_kernel<<<grid, block, 0, stream>>>(f0, f1, f2, f3, boxes, out,
                                                       M, CCH, L, total);
    }
}